// Round 9
// baseline (245.162 us; speedup 1.0000x reference)
//
#include <hip/hip_runtime.h>

// LocalEnergy R9: barrier-free compute path. Each wave owns 32 rows end-to-end:
// GEMM1 (swapped, D[hid][row]) -> wave-PRIVATE H1 LDS region -> GEMM2
// (D[row][col2], all 128 cols) -> masked dot. No __syncthreads between phases
// (only compiler lgkmcnt waits on the wave-local LDS round-trip). One block =
// 128-row tile x all 3 types; 2 barriers/block total.
// B=128, L=2048, E=16, H=128. Out = 128 f32.

typedef short bf16x8 __attribute__((ext_vector_type(8)));
typedef float f32x4  __attribute__((ext_vector_type(4)));

constexpr int Lc  = 2048;
constexpr int SHs = 136;   // H1 row stride (shorts)

union FragU { uint4 u; bf16x8 v; };

__device__ __forceinline__ unsigned short f2bf(float f) {
    union { float f; unsigned u; } v; v.f = f;
    unsigned u = v.u;
    u = u + 0x7FFFu + ((u >> 16) & 1u);   // RTNE
    return (unsigned short)(u >> 16);
}

__device__ __forceinline__ unsigned pkbf(float a, float b) {
    unsigned ua = __float_as_uint(a) + 0x8000u;
    unsigned ub = __float_as_uint(b) + 0x8000u;
    return __builtin_amdgcn_perm(ub, ua, 0x07060302u);  // [lo=bf(a), hi=bf(b)]
}

// ws layout (bytes):
//   W2T[t] @ t*32768          : [col2=128][k=128] bf16 k-contig      (98304)
//   W1T[t] @ 98304 + t*24576  : [hid=128][k=96]   bf16 k-contig      (73728)
//   EB     @ 172032           : [aa=20][16] bf16                     (640)
__global__ __launch_bounds__(256)
void prep_kernel(const float* __restrict__ W1_0, const float* __restrict__ b1_0,
                 const float* __restrict__ W1_1, const float* __restrict__ b1_1,
                 const float* __restrict__ W1_2, const float* __restrict__ b1_2,
                 const float* __restrict__ W2_0, const float* __restrict__ W2_1,
                 const float* __restrict__ W2_2,
                 const float* __restrict__ emb, char* __restrict__ ws,
                 float* __restrict__ out)
{
    const int tid = blockIdx.x * 256 + threadIdx.x;
    const int np  = gridDim.x * 256;
    if (blockIdx.x == 0 && threadIdx.x < 128) out[threadIdx.x] = 0.0f;

    unsigned short* d2 = (unsigned short*)ws;
    for (int o = tid; o < 3 * 16384; o += np) {
        int t = o >> 14, r = o & 16383, col = r >> 7, k = r & 127;
        const float* W2 = (t == 0) ? W2_0 : (t == 1) ? W2_1 : W2_2;
        d2[o] = f2bf(W2[k * 128 + col]);
    }
    // W1^T header: k0=len(t0), k1=cos_t(t1), k2=sin_p(t2), k3=cos_p(t2),
    // k4=b1, k16+j = embedding row j
    unsigned short* d1 = (unsigned short*)(ws + 98304);
    for (int o = tid; o < 3 * 12288; o += np) {
        int t = o / 12288, r = o - t * 12288, hid = r / 96, k = r - hid * 96;
        const int NE16 = (t == 0) ? 32 : (t == 1) ? 48 : 64;
        const int NG   = (t == 2) ? 2 : 1;
        const float* W1 = (t == 0) ? W1_0 : (t == 1) ? W1_1 : W1_2;
        const float* b1 = (t == 0) ? b1_0 : (t == 1) ? b1_1 : b1_2;
        float v = 0.0f;
        if (k >= 16) {
            int j = k - 16;
            if (j < NE16) v = W1[(NG + j) * 128 + hid];
        } else if (k == 4) v = b1[hid];
        else if (t == 0 && k == 0) v = W1_0[hid];
        else if (t == 1 && k == 1) v = W1_1[hid];
        else if (t == 2 && k == 2) v = W1_2[hid];
        else if (t == 2 && k == 3) v = W1_2[128 + hid];
        d1[o] = f2bf(v);
    }
    unsigned short* eb = (unsigned short*)(ws + 172032);
    for (int i = tid; i < 320; i += np) eb[i] = f2bf(emb[i]);
}

struct SMem {
    unsigned short H1s[4][32 * SHs];  // wave-private H1 regions (34816 B)
    float  Rbuf[393];                 // 131 rows x 3
    uint2  geomh[128];                // packed bf16 header per row
    int    seqb[132];
    unsigned short ebuf[320];         // [20][16] bf16
    float  part[4];
};

// One type pass, fully wave-local (no barriers).
template<int TYPE>
__device__ __forceinline__ void type_pass(
    SMem& sm, const char* __restrict__ ws,
    const float* __restrict__ b2, const float* __restrict__ w3,
    int i0, int wv, int q, int c, f32x4& p4)
{
    constexpr int NEMB  = (TYPE == 0) ? 2 : (TYPE == 1) ? 3 : 4;
    constexpr int KS    = (TYPE == 2) ? 3 : 2;
    constexpr int ROWSB = Lc - 1 - TYPE;

    const unsigned short* w1t = (const unsigned short*)(ws + 98304 + TYPE * 24576);
    const unsigned short* w2t = (const unsigned short*)(ws + TYPE * 32768);
    unsigned short* H1w = sm.H1s[wv];

    // ---- GEMM1 (swapped): D[hid][row] for this wave's 32 rows ----
    f32x4 acc1[8][2];
#pragma unroll
    for (int mt = 0; mt < 8; ++mt)
#pragma unroll
        for (int nt = 0; nt < 2; ++nt)
            acc1[mt][nt] = (f32x4){0.f, 0.f, 0.f, 0.f};

#pragma unroll
    for (int ks = 0; ks < KS; ++ks) {
        const int k0 = ks * 32 + q * 8;
        const int j = (k0 - 16) >> 4, off = (k0 - 16) & 15;
        FragU bb[2];
#pragma unroll
        for (int nt = 0; nt < 2; ++nt) {
            const int m = wv * 32 + nt * 16 + c;
            if (ks == 0 && q == 0) {                 // [len,cos_t,sin_p,cos_p,1,0..]
                uint2 g = sm.geomh[m];
                bb[nt].u = make_uint4(g.x, g.y, 0x00003F80u, 0u);
            } else if (k0 >= 16 && j < NEMB) {       // embedding slice
                bb[nt].u = *(const uint4*)&sm.ebuf[sm.seqb[m + j] * 16 + off];
            } else {
                bb[nt].u = make_uint4(0u, 0u, 0u, 0u);
            }
        }
#pragma unroll
        for (int mt = 0; mt < 8; ++mt) {
            FragU a;
            a.u = *(const uint4*)&w1t[(mt * 16 + c) * 96 + ks * 32 + q * 8];
            acc1[mt][0] = __builtin_amdgcn_mfma_f32_16x16x32_bf16(a.v, bb[0].v, acc1[mt][0], 0, 0, 0);
            acc1[mt][1] = __builtin_amdgcn_mfma_f32_16x16x32_bf16(a.v, bb[1].v, acc1[mt][1], 0, 0, 0);
        }
    }

    // ---- H1 = relu -> wave-private LDS (no barrier; same-wave round trip) ----
    const f32x4 z4 = (f32x4){0.f, 0.f, 0.f, 0.f};
#pragma unroll
    for (int mt = 0; mt < 8; ++mt)
#pragma unroll
        for (int nt = 0; nt < 2; ++nt) {
            f32x4 v = __builtin_elementwise_max(acc1[mt][nt], z4);
            uint2 pk;
            pk.x = pkbf(v[0], v[1]);
            pk.y = pkbf(v[2], v[3]);
            *(uint2*)&H1w[(nt * 16 + c) * SHs + mt * 16 + q * 4] = pk;
        }

    // epilogue constants for all 8 col-tiles
    float b2v[8], w3v[8];
#pragma unroll
    for (int nt = 0; nt < 8; ++nt) {
        int col2 = nt * 16 + c;
        b2v[nt] = b2[col2]; w3v[nt] = w3[col2];
    }

    // ---- GEMM2: D[row][col2], all 128 cols for this wave's 32 rows ----
    f32x4 acc2[2][8];
#pragma unroll
    for (int mt = 0; mt < 2; ++mt)
#pragma unroll
        for (int nt = 0; nt < 8; ++nt)
            acc2[mt][nt] = (f32x4){0.f, 0.f, 0.f, 0.f};

#pragma unroll
    for (int ks2 = 0; ks2 < 4; ++ks2) {
        bf16x8 aa0 = *(const bf16x8*)&H1w[(0 * 16 + c) * SHs + ks2 * 32 + q * 8];
        bf16x8 aa1 = *(const bf16x8*)&H1w[(1 * 16 + c) * SHs + ks2 * 32 + q * 8];
#pragma unroll
        for (int nt = 0; nt < 8; ++nt) {
            FragU bf;
            bf.u = *(const uint4*)&w2t[(nt * 16 + c) * 128 + ks2 * 32 + q * 8];
            acc2[0][nt] = __builtin_amdgcn_mfma_f32_16x16x32_bf16(aa0, bf.v, acc2[0][nt], 0, 0, 0);
            acc2[1][nt] = __builtin_amdgcn_mfma_f32_16x16x32_bf16(aa1, bf.v, acc2[1][nt], 0, 0, 0);
        }
    }

    // ---- epilogue: p4 += relu(h2 + b2) * w3 (prefix row-mask fast path) ----
#pragma unroll
    for (int mt = 0; mt < 2; ++mt) {
        int mbase = wv * 32 + mt * 16 + q * 4;
        if (i0 + mbase + 3 < ROWSB) {
#pragma unroll
            for (int nt = 0; nt < 8; ++nt) {
                f32x4 v = acc2[mt][nt] + b2v[nt];
                v = __builtin_elementwise_max(v, z4);
                p4 += v * w3v[nt];
            }
        } else {
#pragma unroll
            for (int rg = 0; rg < 4; ++rg)
                if (i0 + mbase + rg < ROWSB)
#pragma unroll
                    for (int nt = 0; nt < 8; ++nt)
                        p4[rg] += fmaxf(acc2[mt][nt][rg] + b2v[nt], 0.f) * w3v[nt];
        }
    }
}

__global__ __launch_bounds__(256, 3)
void energy_kernel(const float* __restrict__ R, const int* __restrict__ seq,
                   const char* __restrict__ ws,
                   const float* b2_0, const float* b2_1, const float* b2_2,
                   const float* w3_0, const float* w3_1, const float* w3_2,
                   const float* b3_0, const float* b3_1, const float* b3_2,
                   float* __restrict__ out)
{
    __shared__ SMem sm;
    const int tid = threadIdx.x;
    const int b   = blockIdx.y;
    const int i0  = blockIdx.x * 128;
    const int lane = tid & 63, wv = tid >> 6;
    const int q = lane >> 4, c = lane & 15;

    // ---- stage R / seq / ebuf (once per block) ----
    for (int t = tid; t < 393; t += 256) {
        int lr = t / 3, comp = t - lr * 3;
        int row = min(i0 + lr, Lc - 1);
        sm.Rbuf[t] = R[((size_t)b * Lc + row) * 3 + comp];
    }
    for (int t = tid; t < 131; t += 256)
        sm.seqb[t] = seq[b * Lc + min(i0 + t, Lc - 1)];
    {
        const uint4* se = (const uint4*)(ws + 172032);
        for (int t = tid; t < 40; t += 256) ((uint4*)sm.ebuf)[t] = se[t];
    }
    __syncthreads();   // barrier 1: staged data visible to all waves

    // ---- geometry: each wave computes ITS OWN 32 rows (no cross-wave dep) ----
    if (lane < 32) {
        const int r = wv * 32 + lane;
        const float* p0 = &sm.Rbuf[r * 3];
        float ax = p0[3] - p0[0], ay = p0[4] - p0[1], az = p0[5] - p0[2];
        float bx = p0[6] - p0[3], by = p0[7] - p0[4], bz = p0[8] - p0[5];
        float cx = p0[9] - p0[6], cy = p0[10] - p0[7], cz = p0[11] - p0[8];
        float na2 = ax * ax + ay * ay + az * az;
        float len = sqrtf(na2);
        float nb2 = bx * bx + by * by + bz * bz;
        float duv = -(ax * bx + ay * by + az * bz);
        float cost = fminf(fmaxf(duv / sqrtf(na2 * nb2), -1.0f), 1.0f);
        float n1x = ay * bz - az * by, n1y = az * bx - ax * bz, n1z = ax * by - ay * bx;
        float n2x = by * cz - bz * cy, n2y = bz * cx - bx * cz, n2z = bx * cy - by * cx;
        float binv = 1.0f / sqrtf(nb2);
        float ux = bx * binv, uy = by * binv, uz = bz * binv;
        float m1x = n1y * uz - n1z * uy, m1y = n1z * ux - n1x * uz, m1z = n1x * uy - n1y * ux;
        float yv = m1x * n2x + m1y * n2y + m1z * n2z;
        float xv = n1x * n2x + n1y * n2y + n1z * n2z;
        float inv = 1.0f / sqrtf(xv * xv + yv * yv);
        sm.geomh[r] = make_uint2(pkbf(len, cost), pkbf(yv * inv, xv * inv));
    }
    // no barrier: geomh rows [wv*32, wv*32+32) written and read by the same wave

    // ---- three barrier-free type passes ----
    f32x4 p4 = (f32x4){0.f, 0.f, 0.f, 0.f};
    type_pass<0>(sm, ws, b2_0, w3_0, i0, wv, q, c, p4);
    type_pass<1>(sm, ws, b2_1, w3_1, i0, wv, q, c, p4);
    type_pass<2>(sm, ws, b2_2, w3_2, i0, wv, q, c, p4);

    float p = p4[0] + p4[1] + p4[2] + p4[3];
#pragma unroll
    for (int off = 32; off > 0; off >>= 1)
        p += __shfl_down(p, off);
    if (lane == 0) sm.part[wv] = p;
    __syncthreads();   // barrier 2: final reduce
    if (tid == 0) {
        float tot = sm.part[0] + sm.part[1] + sm.part[2] + sm.part[3];
        tot += b3_0[0] * (float)min(Lc - 1 - i0, 128);
        tot += b3_1[0] * (float)min(Lc - 2 - i0, 128);
        tot += b3_2[0] * (float)min(Lc - 3 - i0, 128);
        atomicAdd(&out[b], tot);
    }
}

extern "C" void kernel_launch(void* const* d_in, const int* in_sizes, int n_in,
                              void* d_out, int out_size, void* d_ws, size_t ws_size,
                              hipStream_t stream) {
    const float* R   = (const float*)d_in[0];
    const int*   seq = (const int*)d_in[1];
    const float* emb = (const float*)d_in[2];
    float* out = (float*)d_out;
    char*  ws  = (char*)d_ws;

    prep_kernel<<<dim3(96), dim3(256), 0, stream>>>(
        (const float*)d_in[3],  (const float*)d_in[4],
        (const float*)d_in[9],  (const float*)d_in[10],
        (const float*)d_in[15], (const float*)d_in[16],
        (const float*)d_in[5],  (const float*)d_in[11], (const float*)d_in[17],
        emb, ws, out);

    dim3 grid(16, 128), block(256);
    energy_kernel<<<grid, block, 0, stream>>>(
        R, seq, ws,
        (const float*)d_in[6],  (const float*)d_in[12], (const float*)d_in[18],
        (const float*)d_in[7],  (const float*)d_in[13], (const float*)d_in[19],
        (const float*)d_in[8],  (const float*)d_in[14], (const float*)d_in[20],
        out);
}

// Round 10
// 159.385 us; speedup vs baseline: 1.5382x; 1.5382x over previous
//
#include <hip/hip_runtime.h>

// LocalEnergy R10: R8 structure with pipelined 64-row halves through a
// 128-row H1s: per type = GEMM1(h0),pack,GEMM1(h1),pack, barrier,
// GEMM2(h0),epi,GEMM2(h1),epi, barrier. 8 barriers/block (vs 14), peak
// accumulator 32 regs (vs 64) -> 4 blocks/CU. Geometry+bias folded into
// MFMA K-slots; direct ebuf gather; weights from prepped bf16 ws.
// B=128, L=2048, E=16, H=128. Out = 128 f32.

typedef short bf16x8 __attribute__((ext_vector_type(8)));
typedef float f32x4  __attribute__((ext_vector_type(4)));

constexpr int Lc  = 2048;
constexpr int SHs = 136;   // H1 row stride (shorts)

union FragU { uint4 u; bf16x8 v; };

__device__ __forceinline__ unsigned short f2bf(float f) {
    union { float f; unsigned u; } v; v.f = f;
    unsigned u = v.u;
    u = u + 0x7FFFu + ((u >> 16) & 1u);   // RTNE
    return (unsigned short)(u >> 16);
}

__device__ __forceinline__ unsigned pkbf(float a, float b) {
    unsigned ua = __float_as_uint(a) + 0x8000u;
    unsigned ub = __float_as_uint(b) + 0x8000u;
    return __builtin_amdgcn_perm(ub, ua, 0x07060302u);  // [lo=bf(a), hi=bf(b)]
}

// ws layout (bytes):
//   W2T[t] @ t*32768          : [col2=128][k=128] bf16 k-contig      (98304)
//   W1T[t] @ 98304 + t*24576  : [hid=128][k=96]   bf16 k-contig      (73728)
//   EB     @ 172032           : [aa=20][16] bf16                     (640)
__global__ __launch_bounds__(256)
void prep_kernel(const float* __restrict__ W1_0, const float* __restrict__ b1_0,
                 const float* __restrict__ W1_1, const float* __restrict__ b1_1,
                 const float* __restrict__ W1_2, const float* __restrict__ b1_2,
                 const float* __restrict__ W2_0, const float* __restrict__ W2_1,
                 const float* __restrict__ W2_2,
                 const float* __restrict__ emb, char* __restrict__ ws,
                 float* __restrict__ out)
{
    const int tid = blockIdx.x * 256 + threadIdx.x;
    const int np  = gridDim.x * 256;
    if (blockIdx.x == 0 && threadIdx.x < 128) out[threadIdx.x] = 0.0f;

    unsigned short* d2 = (unsigned short*)ws;
    for (int o = tid; o < 3 * 16384; o += np) {
        int t = o >> 14, r = o & 16383, col = r >> 7, k = r & 127;
        const float* W2 = (t == 0) ? W2_0 : (t == 1) ? W2_1 : W2_2;
        d2[o] = f2bf(W2[k * 128 + col]);
    }
    // W1^T header: k0=len(t0), k1=cos_t(t1), k2=sin_p(t2), k3=cos_p(t2),
    // k4=b1, k16+j = embedding row j
    unsigned short* d1 = (unsigned short*)(ws + 98304);
    for (int o = tid; o < 3 * 12288; o += np) {
        int t = o / 12288, r = o - t * 12288, hid = r / 96, k = r - hid * 96;
        const int NE16 = (t == 0) ? 32 : (t == 1) ? 48 : 64;
        const int NG   = (t == 2) ? 2 : 1;
        const float* W1 = (t == 0) ? W1_0 : (t == 1) ? W1_1 : W1_2;
        const float* b1 = (t == 0) ? b1_0 : (t == 1) ? b1_1 : b1_2;
        float v = 0.0f;
        if (k >= 16) {
            int j = k - 16;
            if (j < NE16) v = W1[(NG + j) * 128 + hid];
        } else if (k == 4) v = b1[hid];
        else if (t == 0 && k == 0) v = W1_0[hid];
        else if (t == 1 && k == 1) v = W1_1[hid];
        else if (t == 2 && k == 2) v = W1_2[hid];
        else if (t == 2 && k == 3) v = W1_2[128 + hid];
        d1[o] = f2bf(v);
    }
    unsigned short* eb = (unsigned short*)(ws + 172032);
    for (int i = tid; i < 320; i += np) eb[i] = f2bf(emb[i]);
}

struct SMem {
    unsigned short H1s[128 * SHs];  // 34816 B (full 128-row tile)
    float  Rbuf[393];               // 131 rows x 3
    uint2  geomh[128];              // packed bf16 header per row
    int    seqb[132];
    unsigned short ebuf[320];       // [20][16] bf16
    float  part[4];
};

template<int TYPE>
__device__ __forceinline__ void type_pass(
    SMem& sm, const char* __restrict__ ws,
    const float* __restrict__ b2, const float* __restrict__ w3,
    int i0, int wv, int q, int c, f32x4& p4)
{
    constexpr int NEMB  = (TYPE == 0) ? 2 : (TYPE == 1) ? 3 : 4;
    constexpr int KS    = (TYPE == 2) ? 3 : 2;
    constexpr int ROWSB = Lc - 1 - TYPE;

    const unsigned short* w1t = (const unsigned short*)(ws + 98304 + TYPE * 24576);
    const unsigned short* w2t = (const unsigned short*)(ws + TYPE * 32768);
    const f32x4 z4 = (f32x4){0.f, 0.f, 0.f, 0.f};

    // A1 frags for this wave's 32-hid chunk (L2-hot)
    FragU A1[2][3];
#pragma unroll
    for (int mt = 0; mt < 2; ++mt)
#pragma unroll
        for (int ks = 0; ks < KS; ++ks)
            A1[mt][ks].u = *(const uint4*)&w1t[(wv * 32 + mt * 16 + c) * 96 + ks * 32 + q * 8];

    // ---- Phase 1: GEMM1 over both 64-row halves (acc regs reused) ----
#pragma unroll
    for (int h = 0; h < 2; ++h) {
        f32x4 acc1[2][4];
#pragma unroll
        for (int mt = 0; mt < 2; ++mt)
#pragma unroll
            for (int nt = 0; nt < 4; ++nt)
                acc1[mt][nt] = z4;

#pragma unroll
        for (int ks = 0; ks < KS; ++ks) {
            const int k0 = ks * 32 + q * 8;
            const int j = (k0 - 16) >> 4, off = (k0 - 16) & 15;
#pragma unroll
            for (int nt = 0; nt < 4; ++nt) {
                const int m = h * 64 + nt * 16 + c;
                FragU bb;
                if (ks == 0 && q == 0) {                 // [len,cos_t,sin_p,cos_p,1,0..]
                    uint2 g = sm.geomh[m];
                    bb.u = make_uint4(g.x, g.y, 0x00003F80u, 0u);
                } else if (k0 >= 16 && j < NEMB) {       // embedding slice
                    bb.u = *(const uint4*)&sm.ebuf[sm.seqb[m + j] * 16 + off];
                } else {
                    bb.u = make_uint4(0u, 0u, 0u, 0u);
                }
                acc1[0][nt] = __builtin_amdgcn_mfma_f32_16x16x32_bf16(A1[0][ks].v, bb.v, acc1[0][nt], 0, 0, 0);
                acc1[1][nt] = __builtin_amdgcn_mfma_f32_16x16x32_bf16(A1[1][ks].v, bb.v, acc1[1][nt], 0, 0, 0);
            }
        }

        // H1 = relu -> H1s (packed 8B writes; bias/geom already folded)
#pragma unroll
        for (int mt = 0; mt < 2; ++mt)
#pragma unroll
            for (int nt = 0; nt < 4; ++nt) {
                f32x4 v = __builtin_elementwise_max(acc1[mt][nt], z4);
                uint2 pk;
                pk.x = pkbf(v[0], v[1]);
                pk.y = pkbf(v[2], v[3]);
                *(uint2*)&sm.H1s[(h * 64 + nt * 16 + c) * SHs + wv * 32 + mt * 16 + q * 4] = pk;
            }
    }

    // W2 frags + epilogue consts before the barrier (latency overlapped)
    FragU B2[2][4];
#pragma unroll
    for (int nt = 0; nt < 2; ++nt)
#pragma unroll
        for (int ks = 0; ks < 4; ++ks)
            B2[nt][ks].u = *(const uint4*)&w2t[(wv * 32 + nt * 16 + c) * 128 + ks * 32 + q * 8];
    float b2v[2], w3v[2];
#pragma unroll
    for (int nt = 0; nt < 2; ++nt) {
        int col2 = wv * 32 + nt * 16 + c;
        b2v[nt] = b2[col2]; w3v[nt] = w3[col2];
    }
    __syncthreads();   // H1s (all 128 rows) ready

    // ---- Phase 2: GEMM2 + epilogue over both halves (acc regs reused) ----
#pragma unroll
    for (int h = 0; h < 2; ++h) {
        f32x4 acc2[4][2];
#pragma unroll
        for (int mt = 0; mt < 4; ++mt)
#pragma unroll
            for (int nt = 0; nt < 2; ++nt)
                acc2[mt][nt] = z4;
#pragma unroll
        for (int ks2 = 0; ks2 < 4; ++ks2)
#pragma unroll
            for (int mt = 0; mt < 4; ++mt) {
                bf16x8 aa = *(const bf16x8*)&sm.H1s[(h * 64 + mt * 16 + c) * SHs + ks2 * 32 + q * 8];
                acc2[mt][0] = __builtin_amdgcn_mfma_f32_16x16x32_bf16(aa, B2[0][ks2].v, acc2[mt][0], 0, 0, 0);
                acc2[mt][1] = __builtin_amdgcn_mfma_f32_16x16x32_bf16(aa, B2[1][ks2].v, acc2[mt][1], 0, 0, 0);
            }

#pragma unroll
        for (int mt = 0; mt < 4; ++mt) {
            int mbase = h * 64 + mt * 16 + q * 4;
            if (i0 + mbase + 3 < ROWSB) {
#pragma unroll
                for (int nt = 0; nt < 2; ++nt) {
                    f32x4 v = acc2[mt][nt] + b2v[nt];
                    v = __builtin_elementwise_max(v, z4);
                    p4 += v * w3v[nt];
                }
            } else {
#pragma unroll
                for (int rg = 0; rg < 4; ++rg)
                    if (i0 + mbase + rg < ROWSB) {
                        p4[rg] += fmaxf(acc2[mt][0][rg] + b2v[0], 0.f) * w3v[0];
                        p4[rg] += fmaxf(acc2[mt][1][rg] + b2v[1], 0.f) * w3v[1];
                    }
            }
        }
    }
    __syncthreads();   // WAR: H1s reused by next type
}

__global__ __launch_bounds__(256, 4)
void energy_kernel(const float* __restrict__ R, const int* __restrict__ seq,
                   const char* __restrict__ ws,
                   const float* b2_0, const float* b2_1, const float* b2_2,
                   const float* w3_0, const float* w3_1, const float* w3_2,
                   const float* b3_0, const float* b3_1, const float* b3_2,
                   float* __restrict__ out)
{
    __shared__ SMem sm;
    const int tid = threadIdx.x;
    const int b   = blockIdx.y;
    const int i0  = blockIdx.x * 128;
    const int lane = tid & 63, wv = tid >> 6;
    const int q = lane >> 4, c = lane & 15;

    // ---- stage R / seq / ebuf (once per block) ----
    for (int t = tid; t < 393; t += 256) {
        int lr = t / 3, comp = t - lr * 3;
        int row = min(i0 + lr, Lc - 1);
        sm.Rbuf[t] = R[((size_t)b * Lc + row) * 3 + comp];
    }
    for (int t = tid; t < 131; t += 256)
        sm.seqb[t] = seq[b * Lc + min(i0 + t, Lc - 1)];
    {
        const uint4* se = (const uint4*)(ws + 172032);
        for (int t = tid; t < 40; t += 256) ((uint4*)sm.ebuf)[t] = se[t];
    }
    __syncthreads();

    // ---- geometry -> packed bf16 header (once per block) ----
    if (tid < 128) {
        const float* p0 = &sm.Rbuf[tid * 3];
        float ax = p0[3] - p0[0], ay = p0[4] - p0[1], az = p0[5] - p0[2];
        float bx = p0[6] - p0[3], by = p0[7] - p0[4], bz = p0[8] - p0[5];
        float cx = p0[9] - p0[6], cy = p0[10] - p0[7], cz = p0[11] - p0[8];
        float na2 = ax * ax + ay * ay + az * az;
        float len = sqrtf(na2);
        float nb2 = bx * bx + by * by + bz * bz;
        float duv = -(ax * bx + ay * by + az * bz);
        float cost = fminf(fmaxf(duv / sqrtf(na2 * nb2), -1.0f), 1.0f);
        float n1x = ay * bz - az * by, n1y = az * bx - ax * bz, n1z = ax * by - ay * bx;
        float n2x = by * cz - bz * cy, n2y = bz * cx - bx * cz, n2z = bx * cy - by * cx;
        float binv = 1.0f / sqrtf(nb2);
        float ux = bx * binv, uy = by * binv, uz = bz * binv;
        float m1x = n1y * uz - n1z * uy, m1y = n1z * ux - n1x * uz, m1z = n1x * uy - n1y * ux;
        float yv = m1x * n2x + m1y * n2y + m1z * n2z;
        float xv = n1x * n2x + n1y * n2y + n1z * n2z;
        float inv = 1.0f / sqrtf(xv * xv + yv * yv);
        sm.geomh[tid] = make_uint2(pkbf(len, cost), pkbf(yv * inv, xv * inv));
    }
    __syncthreads();

    // ---- three type passes (2 barriers each) ----
    f32x4 p4 = (f32x4){0.f, 0.f, 0.f, 0.f};
    type_pass<0>(sm, ws, b2_0, w3_0, i0, wv, q, c, p4);
    type_pass<1>(sm, ws, b2_1, w3_1, i0, wv, q, c, p4);
    type_pass<2>(sm, ws, b2_2, w3_2, i0, wv, q, c, p4);

    float p = p4[0] + p4[1] + p4[2] + p4[3];
#pragma unroll
    for (int off = 32; off > 0; off >>= 1)
        p += __shfl_down(p, off);
    if (lane == 0) sm.part[wv] = p;
    __syncthreads();
    if (tid == 0) {
        float tot = sm.part[0] + sm.part[1] + sm.part[2] + sm.part[3];
        tot += b3_0[0] * (float)min(Lc - 1 - i0, 128);
        tot += b3_1[0] * (float)min(Lc - 2 - i0, 128);
        tot += b3_2[0] * (float)min(Lc - 3 - i0, 128);
        atomicAdd(&out[b], tot);
    }
}

extern "C" void kernel_launch(void* const* d_in, const int* in_sizes, int n_in,
                              void* d_out, int out_size, void* d_ws, size_t ws_size,
                              hipStream_t stream) {
    const float* R   = (const float*)d_in[0];
    const int*   seq = (const int*)d_in[1];
    const float* emb = (const float*)d_in[2];
    float* out = (float*)d_out;
    char*  ws  = (char*)d_ws;

    prep_kernel<<<dim3(96), dim3(256), 0, stream>>>(
        (const float*)d_in[3],  (const float*)d_in[4],
        (const float*)d_in[9],  (const float*)d_in[10],
        (const float*)d_in[15], (const float*)d_in[16],
        (const float*)d_in[5],  (const float*)d_in[11], (const float*)d_in[17],
        emb, ws, out);

    dim3 grid(16, 128), block(256);
    energy_kernel<<<grid, block, 0, stream>>>(
        R, seq, ws,
        (const float*)d_in[6],  (const float*)d_in[12], (const float*)d_in[18],
        (const float*)d_in[7],  (const float*)d_in[13], (const float*)d_in[19],
        (const float*)d_in[8],  (const float*)d_in[14], (const float*)d_in[20],
        out);
}

// Round 11
// 154.381 us; speedup vs baseline: 1.5880x; 1.0324x over previous
//
#include <hip/hip_runtime.h>

// LocalEnergy R11: R10 structure, both GEMMs on mfma_f32_32x32x16_bf16
// (half the MFMA instruction count; K-step=16 matches emb-row granularity so
// no zero-padded K blocks). Header (geom+1.0+bias) rides K-step 0. Each wave:
// GEMM1 = 32 hid x 128 rows; GEMM2 = 128 rows x 32 cols (per-lane scalar
// b2/w3). 8 barriers/block. B=128, L=2048, E=16, H=128. Out = 128 f32.

typedef short bf16x8  __attribute__((ext_vector_type(8)));
typedef float f32x4   __attribute__((ext_vector_type(4)));
typedef float f32x16  __attribute__((ext_vector_type(16)));

constexpr int Lc  = 2048;
constexpr int SHs = 136;   // H1 row stride (shorts) = 272 B

union FragU { uint4 u; bf16x8 v; };

__device__ __forceinline__ unsigned short f2bf(float f) {
    union { float f; unsigned u; } v; v.f = f;
    unsigned u = v.u;
    u = u + 0x7FFFu + ((u >> 16) & 1u);   // RTNE
    return (unsigned short)(u >> 16);
}

__device__ __forceinline__ unsigned pkbf(float a, float b) {
    unsigned ua = __float_as_uint(a) + 0x8000u;
    unsigned ub = __float_as_uint(b) + 0x8000u;
    return __builtin_amdgcn_perm(ub, ua, 0x07060302u);  // [lo=bf(a), hi=bf(b)]
}

// ws layout (bytes) — unchanged from R10:
//   W2T[t] @ t*32768          : [col2=128][k=128] bf16 k-contig      (98304)
//   W1T[t] @ 98304 + t*24576  : [hid=128][k=96]   bf16 k-contig      (73728)
//     header slots: k0=len(t0), k1=cos_t(t1), k2=sin_p(t2), k3=cos_p(t2),
//     k4=b1, k16+j = embedding row j
//   EB     @ 172032           : [aa=20][16] bf16                     (640)
__global__ __launch_bounds__(256)
void prep_kernel(const float* __restrict__ W1_0, const float* __restrict__ b1_0,
                 const float* __restrict__ W1_1, const float* __restrict__ b1_1,
                 const float* __restrict__ W1_2, const float* __restrict__ b1_2,
                 const float* __restrict__ W2_0, const float* __restrict__ W2_1,
                 const float* __restrict__ W2_2,
                 const float* __restrict__ emb, char* __restrict__ ws,
                 float* __restrict__ out)
{
    const int tid = blockIdx.x * 256 + threadIdx.x;
    const int np  = gridDim.x * 256;
    if (blockIdx.x == 0 && threadIdx.x < 128) out[threadIdx.x] = 0.0f;

    unsigned short* d2 = (unsigned short*)ws;
    for (int o = tid; o < 3 * 16384; o += np) {
        int t = o >> 14, r = o & 16383, col = r >> 7, k = r & 127;
        const float* W2 = (t == 0) ? W2_0 : (t == 1) ? W2_1 : W2_2;
        d2[o] = f2bf(W2[k * 128 + col]);
    }
    unsigned short* d1 = (unsigned short*)(ws + 98304);
    for (int o = tid; o < 3 * 12288; o += np) {
        int t = o / 12288, r = o - t * 12288, hid = r / 96, k = r - hid * 96;
        const int NE16 = (t == 0) ? 32 : (t == 1) ? 48 : 64;
        const int NG   = (t == 2) ? 2 : 1;
        const float* W1 = (t == 0) ? W1_0 : (t == 1) ? W1_1 : W1_2;
        const float* b1 = (t == 0) ? b1_0 : (t == 1) ? b1_1 : b1_2;
        float v = 0.0f;
        if (k >= 16) {
            int j = k - 16;
            if (j < NE16) v = W1[(NG + j) * 128 + hid];
        } else if (k == 4) v = b1[hid];
        else if (t == 0 && k == 0) v = W1_0[hid];
        else if (t == 1 && k == 1) v = W1_1[hid];
        else if (t == 2 && k == 2) v = W1_2[hid];
        else if (t == 2 && k == 3) v = W1_2[128 + hid];
        d1[o] = f2bf(v);
    }
    unsigned short* eb = (unsigned short*)(ws + 172032);
    for (int i = tid; i < 320; i += np) eb[i] = f2bf(emb[i]);
}

struct SMem {
    unsigned short H1s[128 * SHs];  // 34816 B
    float  Rbuf[393];               // 131 rows x 3
    uint2  geomh[128];              // packed bf16 header per row
    int    seqb[132];
    unsigned short ebuf[320];       // [20][16] bf16
    float  part[4];
};

template<int TYPE>
__device__ __forceinline__ void type_pass(
    SMem& sm, const char* __restrict__ ws,
    const float* __restrict__ b2, const float* __restrict__ w3,
    int i0, int wv, int ln31, int hi, f32x4& p4)
{
    constexpr int NEMB  = (TYPE == 0) ? 2 : (TYPE == 1) ? 3 : 4;
    constexpr int STEPS = 1 + NEMB;          // header + emb K-steps (K=16 each)
    constexpr int ROWSB = Lc - 1 - TYPE;

    const unsigned short* w1t = (const unsigned short*)(ws + 98304 + TYPE * 24576);
    const unsigned short* w2t = (const unsigned short*)(ws + TYPE * 32768);
    const f32x4 z4 = (f32x4){0.f, 0.f, 0.f, 0.f};

    // A1 frags: W1T[m=hid=wv*32+ln31][k=s*16+hi*8 ..+8]  (L2-hot)
    FragU A1[STEPS];
#pragma unroll
    for (int s = 0; s < STEPS; ++s)
        A1[s].u = *(const uint4*)&w1t[(wv * 32 + ln31) * 96 + s * 16 + hi * 8];

    // ---- Phase 1: GEMM1 over both 64-row halves (acc regs reused) ----
#pragma unroll
    for (int h = 0; h < 2; ++h) {
        f32x16 acc1[2];
        acc1[0] = (f32x16)(0.f);
        acc1[1] = (f32x16)(0.f);

#pragma unroll
        for (int s = 0; s < STEPS; ++s) {
#pragma unroll
            for (int rt = 0; rt < 2; ++rt) {
                const int row = h * 64 + rt * 32 + ln31;
                FragU bb;
                if (s == 0) {                      // header [len,cos_t,sin_p,cos_p,1,0..]
                    if (hi == 0) {
                        uint2 g = sm.geomh[row];
                        bb.u = make_uint4(g.x, g.y, 0x00003F80u, 0u);
                    } else {
                        bb.u = make_uint4(0u, 0u, 0u, 0u);
                    }
                } else {                           // embedding row j = s-1
                    bb.u = *(const uint4*)&sm.ebuf[sm.seqb[row + (s - 1)] * 16 + hi * 8];
                }
                acc1[rt] = __builtin_amdgcn_mfma_f32_32x32x16_bf16(A1[s].v, bb.v, acc1[rt], 0, 0, 0);
            }
        }

        // H1 = relu -> H1s. D: col=ln31=row, m(hid)= (reg&3)+8*(reg>>2)+4*hi.
#pragma unroll
        for (int rt = 0; rt < 2; ++rt) {
            const int row = h * 64 + rt * 32 + ln31;
#pragma unroll
            for (int g = 0; g < 4; ++g) {
                float v0 = fmaxf(acc1[rt][4 * g + 0], 0.f);
                float v1 = fmaxf(acc1[rt][4 * g + 1], 0.f);
                float v2 = fmaxf(acc1[rt][4 * g + 2], 0.f);
                float v3 = fmaxf(acc1[rt][4 * g + 3], 0.f);
                uint2 pk;
                pk.x = pkbf(v0, v1);
                pk.y = pkbf(v2, v3);
                *(uint2*)&sm.H1s[row * SHs + wv * 32 + 8 * g + 4 * hi] = pk;
            }
        }
    }

    // B2 frags + per-lane epilogue consts before the barrier (latency overlap)
    FragU B2[8];
#pragma unroll
    for (int s2 = 0; s2 < 8; ++s2)
        B2[s2].u = *(const uint4*)&w2t[(wv * 32 + ln31) * 128 + s2 * 16 + hi * 8];
    const float b2v = b2[wv * 32 + ln31];
    const float w3v = w3[wv * 32 + ln31];
    __syncthreads();   // H1s (all 128 rows) ready

    // ---- Phase 2: GEMM2 + epilogue over both halves (acc regs reused) ----
#pragma unroll
    for (int h = 0; h < 2; ++h) {
        f32x16 acc2[2];
        acc2[0] = (f32x16)(0.f);
        acc2[1] = (f32x16)(0.f);
#pragma unroll
        for (int s2 = 0; s2 < 8; ++s2)
#pragma unroll
            for (int rt = 0; rt < 2; ++rt) {
                const int row = h * 64 + rt * 32 + ln31;
                bf16x8 aa = *(const bf16x8*)&sm.H1s[row * SHs + s2 * 16 + hi * 8];
                acc2[rt] = __builtin_amdgcn_mfma_f32_32x32x16_bf16(aa, B2[s2].v, acc2[rt], 0, 0, 0);
            }

        // epilogue: p4 += relu(h2 + b2) * w3. D: col=ln31=col2,
        // m(row) = rt*32 + (reg&3) + 8*(reg>>2) + 4*hi (+h*64).
#pragma unroll
        for (int rt = 0; rt < 2; ++rt) {
#pragma unroll
            for (int g = 0; g < 4; ++g) {
                const int rbase = i0 + h * 64 + rt * 32 + 8 * g + 4 * hi;
                f32x4 v;
                v[0] = acc2[rt][4 * g + 0]; v[1] = acc2[rt][4 * g + 1];
                v[2] = acc2[rt][4 * g + 2]; v[3] = acc2[rt][4 * g + 3];
                v = __builtin_elementwise_max(v + b2v, z4);
                if (rbase + 3 < ROWSB) {
                    p4 += v * w3v;
                } else {
#pragma unroll
                    for (int rg = 0; rg < 4; ++rg)
                        if (rbase + rg < ROWSB) p4[rg] += v[rg] * w3v;
                }
            }
        }
    }
    __syncthreads();   // WAR: H1s reused by next type
}

__global__ __launch_bounds__(256, 4)
void energy_kernel(const float* __restrict__ R, const int* __restrict__ seq,
                   const char* __restrict__ ws,
                   const float* b2_0, const float* b2_1, const float* b2_2,
                   const float* w3_0, const float* w3_1, const float* w3_2,
                   const float* b3_0, const float* b3_1, const float* b3_2,
                   float* __restrict__ out)
{
    __shared__ SMem sm;
    const int tid = threadIdx.x;
    const int b   = blockIdx.y;
    const int i0  = blockIdx.x * 128;
    const int lane = tid & 63, wv = tid >> 6;
    const int ln31 = lane & 31, hi = lane >> 5;

    // ---- stage R / seq / ebuf (once per block) ----
    for (int t = tid; t < 393; t += 256) {
        int lr = t / 3, comp = t - lr * 3;
        int row = min(i0 + lr, Lc - 1);
        sm.Rbuf[t] = R[((size_t)b * Lc + row) * 3 + comp];
    }
    for (int t = tid; t < 131; t += 256)
        sm.seqb[t] = seq[b * Lc + min(i0 + t, Lc - 1)];
    {
        const uint4* se = (const uint4*)(ws + 172032);
        for (int t = tid; t < 40; t += 256) ((uint4*)sm.ebuf)[t] = se[t];
    }
    __syncthreads();

    // ---- geometry -> packed bf16 header (once per block) ----
    if (tid < 128) {
        const float* p0 = &sm.Rbuf[tid * 3];
        float ax = p0[3] - p0[0], ay = p0[4] - p0[1], az = p0[5] - p0[2];
        float bx = p0[6] - p0[3], by = p0[7] - p0[4], bz = p0[8] - p0[5];
        float cx = p0[9] - p0[6], cy = p0[10] - p0[7], cz = p0[11] - p0[8];
        float na2 = ax * ax + ay * ay + az * az;
        float len = sqrtf(na2);
        float nb2 = bx * bx + by * by + bz * bz;
        float duv = -(ax * bx + ay * by + az * bz);
        float cost = fminf(fmaxf(duv / sqrtf(na2 * nb2), -1.0f), 1.0f);
        float n1x = ay * bz - az * by, n1y = az * bx - ax * bz, n1z = ax * by - ay * bx;
        float n2x = by * cz - bz * cy, n2y = bz * cx - bx * cz, n2z = bx * cy - by * cx;
        float binv = 1.0f / sqrtf(nb2);
        float ux = bx * binv, uy = by * binv, uz = bz * binv;
        float m1x = n1y * uz - n1z * uy, m1y = n1z * ux - n1x * uz, m1z = n1x * uy - n1y * ux;
        float yv = m1x * n2x + m1y * n2y + m1z * n2z;
        float xv = n1x * n2x + n1y * n2y + n1z * n2z;
        float inv = 1.0f / sqrtf(xv * xv + yv * yv);
        sm.geomh[tid] = make_uint2(pkbf(len, cost), pkbf(yv * inv, xv * inv));
    }
    __syncthreads();

    // ---- three type passes (2 barriers each) ----
    f32x4 p4 = (f32x4){0.f, 0.f, 0.f, 0.f};
    type_pass<0>(sm, ws, b2_0, w3_0, i0, wv, ln31, hi, p4);
    type_pass<1>(sm, ws, b2_1, w3_1, i0, wv, ln31, hi, p4);
    type_pass<2>(sm, ws, b2_2, w3_2, i0, wv, ln31, hi, p4);

    float p = p4[0] + p4[1] + p4[2] + p4[3];
#pragma unroll
    for (int off = 32; off > 0; off >>= 1)
        p += __shfl_down(p, off);
    if (lane == 0) sm.part[wv] = p;
    __syncthreads();
    if (tid == 0) {
        float tot = sm.part[0] + sm.part[1] + sm.part[2] + sm.part[3];
        tot += b3_0[0] * (float)min(Lc - 1 - i0, 128);
        tot += b3_1[0] * (float)min(Lc - 2 - i0, 128);
        tot += b3_2[0] * (float)min(Lc - 3 - i0, 128);
        atomicAdd(&out[b], tot);
    }
}

extern "C" void kernel_launch(void* const* d_in, const int* in_sizes, int n_in,
                              void* d_out, int out_size, void* d_ws, size_t ws_size,
                              hipStream_t stream) {
    const float* R   = (const float*)d_in[0];
    const int*   seq = (const int*)d_in[1];
    const float* emb = (const float*)d_in[2];
    float* out = (float*)d_out;
    char*  ws  = (char*)d_ws;

    prep_kernel<<<dim3(96), dim3(256), 0, stream>>>(
        (const float*)d_in[3],  (const float*)d_in[4],
        (const float*)d_in[9],  (const float*)d_in[10],
        (const float*)d_in[15], (const float*)d_in[16],
        (const float*)d_in[5],  (const float*)d_in[11], (const float*)d_in[17],
        emb, ws, out);

    dim3 grid(16, 128), block(256);
    energy_kernel<<<grid, block, 0, stream>>>(
        R, seq, ws,
        (const float*)d_in[6],  (const float*)d_in[12], (const float*)d_in[18],
        (const float*)d_in[7],  (const float*)d_in[13], (const float*)d_in[19],
        (const float*)d_in[8],  (const float*)d_in[14], (const float*)d_in[20],
        out);
}